// Round 8
// baseline (444.097 us; speedup 1.0000x reference)
//
#include <hip/hip_runtime.h>

// N=512 state dim, L=16384 steps, chunk T=1024, P=16 chunks.
#define NDIM 512
#define LSEQ 16384
#define TCH  1024
#define PCH  16
#define MM   (NDIM * NDIM)

#define DTF  (1.0f/16384.0f)
#define DT2F (0.5f/16384.0f)

// ---------------------------------------------------------------------------
// gkt: 32x32-output GEMM task, 4-wave K-split with private LDS staging and
// cross-wave LDS reduce. K must be a multiple of 64. (R4-verified core: 1-deep
// register prefetch, no per-step barriers; only barrier is pre-reduce.)
// Optional epilogue (gr0>=0, used by W21 writers): also emit Ab = 2*val
// (strictly-lower blocks, no -I) and atomicAdd the Bb row-partial
// dt*val.Bv into Bbc and V[:,0]. gr0/gc0 = global coords of D's origin.
// NOTE when one block runs several gkt calls back-to-back the CALLER must
// __syncthreads() between calls (LDS reuse + D->B visibility).
// ---------------------------------------------------------------------------
__device__ __forceinline__ void gkt(float* smem,
    const float* A, int lda, const float* B, int ldb,
    float* D, int ldd, int row0, int col0, int K, float alpha,
    float* Abe = nullptr, float* Bbce = nullptr, float* Ve = nullptr,
    const float* Bve = nullptr, int gr0 = -1, int gc0 = 0)
{
    const int tid  = threadIdx.x;
    const int w    = tid >> 6;
    const int lane = tid & 63;
    const int ty = lane >> 3, tx = lane & 7;          // 8x8 lane grid, 4x4 micro

    float* As = smem + w * 1152;          // As[k][r] = As[k*36 + r]
    float* Bs = As + 576;                 // Bs[k][c] = Bs[k*36 + c]

    const int Kc    = K >> 2;             // per-wave K chunk (mult of 16)
    const int steps = Kc >> 4;
    const int kbase = w * Kc;

    const int ar  = lane >> 2, acg = (lane & 3) * 4;  // A-stage lane map
    const int bkr = lane >> 3, bcg = (lane & 7) * 4;  // B-stage lane map
    const float* Ap0 = A + (size_t)(row0 + ar) * lda + kbase + acg;
    const float* Ap1 = Ap0 + (size_t)16 * lda;
    const float* Bp0 = B + (size_t)(kbase + bkr) * ldb + col0 + bcg;
    const float* Bp1 = Bp0 + (size_t)8 * ldb;

    float4 av0 = *(const float4*)Ap0;
    float4 av1 = *(const float4*)Ap1;
    float4 bv0 = *(const float4*)Bp0;
    float4 bv1 = *(const float4*)Bp1;

    float acc[4][4] = {};

    for (int s = 0; s < steps; ++s) {
        As[(acg + 0) * 36 + ar] = av0.x;
        As[(acg + 1) * 36 + ar] = av0.y;
        As[(acg + 2) * 36 + ar] = av0.z;
        As[(acg + 3) * 36 + ar] = av0.w;
        As[(acg + 0) * 36 + ar + 16] = av1.x;
        As[(acg + 1) * 36 + ar + 16] = av1.y;
        As[(acg + 2) * 36 + ar + 16] = av1.z;
        As[(acg + 3) * 36 + ar + 16] = av1.w;
        *(float4*)(Bs + bkr * 36 + bcg)       = bv0;
        *(float4*)(Bs + (bkr + 8) * 36 + bcg) = bv1;

        if (s + 1 < steps) {
            int ko = (s + 1) * 16;
            av0 = *(const float4*)(Ap0 + ko);
            av1 = *(const float4*)(Ap1 + ko);
            bv0 = *(const float4*)(Bp0 + (size_t)ko * ldb);
            bv1 = *(const float4*)(Bp1 + (size_t)ko * ldb);
        }

#pragma unroll
        for (int kk = 0; kk < 16; ++kk) {
            float4 a = *(const float4*)(As + kk * 36 + 4 * ty);
            float4 b = *(const float4*)(Bs + kk * 36 + 4 * tx);
            acc[0][0] += a.x * b.x; acc[0][1] += a.x * b.y; acc[0][2] += a.x * b.z; acc[0][3] += a.x * b.w;
            acc[1][0] += a.y * b.x; acc[1][1] += a.y * b.y; acc[1][2] += a.y * b.z; acc[1][3] += a.y * b.w;
            acc[2][0] += a.z * b.x; acc[2][1] += a.z * b.y; acc[2][2] += a.z * b.z; acc[2][3] += a.z * b.w;
            acc[3][0] += a.w * b.x; acc[3][1] += a.w * b.y; acc[3][2] += a.w * b.z; acc[3][3] += a.w * b.w;
        }
    }

    float* red = smem + w * 1152;
#pragma unroll
    for (int i = 0; i < 4; ++i)
        *(float4*)(red + (4 * ty + i) * 32 + 4 * tx) =
            make_float4(acc[i][0], acc[i][1], acc[i][2], acc[i][3]);
    __syncthreads();

    float4 s0 = *(const float4*)(smem + 0 * 1152 + tid * 4);
    float4 s1 = *(const float4*)(smem + 1 * 1152 + tid * 4);
    float4 s2 = *(const float4*)(smem + 2 * 1152 + tid * 4);
    float4 s3 = *(const float4*)(smem + 3 * 1152 + tid * 4);
    float4 r4 = make_float4(alpha * (s0.x + s1.x + s2.x + s3.x),
                            alpha * (s0.y + s1.y + s2.y + s3.y),
                            alpha * (s0.z + s1.z + s2.z + s3.z),
                            alpha * (s0.w + s1.w + s2.w + s3.w));
    int r = tid >> 3, c = (tid & 7) * 4;
    // scalar stores: D base may be only 4B-aligned (V+m slab writes, m=1,2)
    float* dp = D + (size_t)(row0 + r) * ldd + col0 + c;
    dp[0] = r4.x; dp[1] = r4.y; dp[2] = r4.z; dp[3] = r4.w;

    if (gr0 >= 0) {   // W21 writer: emit Ab = 2*W21 and Bb row-partials
        int grow = gr0 + row0 + r, gcol = gc0 + col0 + c;
        *(float4*)(Abe + (size_t)grow * NDIM + gcol) =
            make_float4(2.f * r4.x, 2.f * r4.y, 2.f * r4.z, 2.f * r4.w);
        float pv = r4.x * Bve[gcol]     + r4.y * Bve[gcol + 1]
                 + r4.z * Bve[gcol + 2] + r4.w * Bve[gcol + 3];
        pv += __shfl_xor(pv, 1, 64);     // reduce across the 8 col-threads
        pv += __shfl_xor(pv, 2, 64);     // of this row (lane-aligned group)
        pv += __shfl_xor(pv, 4, 64);
        if ((tid & 7) == 0) {
            float bb = DTF * pv;
            atomicAdd(&Bbce[grow], bb);
            atomicAdd(&Ve[(size_t)grow * TCH], bb);
        }
    }
}

// triangular tile decode: t -> (it, jt) with jt <= it
__device__ __forceinline__ void tri_decode(int t, int& it, int& jt)
{
    it = (int)((sqrtf(8.f * (float)t + 1.f) - 1.f) * 0.5f);
    while ((it + 1) * (it + 2) / 2 <= t) ++it;
    while (it * (it + 1) / 2 > t) --it;
    jt = t - it * (it + 1) / 2;
}

// ---------------------------------------------------------------------------
// scan_task: one Kogge-Stone task (4 waves = 4 (p,i) pairs), G lower-tri.
// ---------------------------------------------------------------------------
__device__ __forceinline__ void scan_task(int task, const float* G,
    const float* Zold, float* Znew, const float* hs, float* Hmat,
    float* hfin, int o, int last)
{
    int wid = task * 4 + (threadIdx.x >> 6);
    int lane = threadIdx.x & 63;
    int p = wid & (PCH - 1), i = wid >> 4;
    float dot = 0.f;
    if (p >= o) {
        const float* gr = G + (size_t)i * NDIM;
        const float* zc = Zold + (size_t)(p - o) * NDIM;
        int rmax = i >> 6;
        for (int r = 0; r <= rmax; ++r) {
            int k = (r << 6) + lane;
            if (k <= i) dot += gr[k] * zc[k];
        }
#pragma unroll
        for (int off = 32; off; off >>= 1) dot += __shfl_xor(dot, off, 64);
    }
    if (lane == 0) {
        float z = Zold[(size_t)p * NDIM + i] + dot;
        Znew[(size_t)p * NDIM + i] = z;
        if (last) {
            if (p < PCH - 1) Hmat[(size_t)(p + 1) * NDIM + i] = z;
            else hfin[i] = z;
            if (p == 0) Hmat[i] = hs[i];
        }
    }
}

// ---------------------------------------------------------------------------
// zero_diag: fused one-time init.
//  t<8  : invert diagonal 64x64 block t of (I - dt/2*A) into W; also emit the
//         matching Ab diag block (2X - I, exact-zero uppers) and the DIAG part
//         of Bb = dt*W@Bv (plain store — exactly one writer per row; pair
//         kernels atomicAdd the off-diag parts on top afterwards).
//  8<=t<56: zero strictly-upper part of diagonal 64-block d of power buffer q
//         (P0..GD) — the only upper entries the 64-aligned K-clips ever read.
//  t==56: Crows[0] = C.
// ---------------------------------------------------------------------------
__global__ __launch_bounds__(256) void zero_diag(const float* __restrict__ A,
    float* __restrict__ W, float* __restrict__ P0, float* __restrict__ Ab,
    float* __restrict__ Bbc, float* __restrict__ V, float* __restrict__ Crows,
    const float* __restrict__ Bv, const float* __restrict__ C)
{
    __shared__ float sh[64][65];
    const int t = blockIdx.x, tid = threadIdx.x;
    if (t < 8) {
        const int base = t * 64;
        for (int idx = tid; idx < 4096; idx += 256) {
            int r = idx >> 6, c = idx & 63;
            sh[r][c] = ((r == c) ? 1.f : 0.f)
                     - DT2F * A[(size_t)(base + r) * NDIM + base + c];
        }
        __syncthreads();
        if (tid < 64) {
            const int lane = tid;
            float xcol[64];
#pragma unroll
            for (int i = 0; i < 64; ++i) {
                float dot = 0.f;
#pragma unroll
                for (int k = 0; k < i; ++k) dot += sh[i][k] * xcol[k];
                xcol[i] = (((lane == i) ? 1.f : 0.f) - dot) / sh[i][i];
            }
            const float bvv = Bv[base + lane];
#pragma unroll
            for (int k = 0; k < 64; ++k) {
                float xv = xcol[k];
                W[(size_t)(base + k) * NDIM + base + lane] = xv;
                Ab[(size_t)(base + k) * NDIM + base + lane] =
                    2.f * xv - ((k == lane) ? 1.f : 0.f);
                float pv = xv * bvv;
#pragma unroll
                for (int off = 32; off; off >>= 1) pv += __shfl_xor(pv, off, 64);
                if (lane == 0) {
                    float bb = DTF * pv;
                    Bbc[base + k] = bb;                  // plain store (base)
                    V[(size_t)(base + k) * TCH] = bb;
                }
            }
        }
    } else if (t < 56) {
        const int q = (t - 8) >> 3, d = (t - 8) & 7;
        float* buf = P0 + (size_t)q * MM;
        for (int idx = tid; idx < 4096; idx += 256) {
            int r = idx >> 6, c = idx & 63;
            if (c > r) buf[(size_t)(d * 64 + r) * NDIM + d * 64 + c] = 0.f;
        }
    } else {
        Crows[tid]       = C[tid];
        Crows[tid + 256] = C[tid + 256];
    }
}

// ---------------------------------------------------------------------------
// pair64: merged s=64 pair level — one block per pair, both phases.
//   T = A21 @ W11 (4 tiles), then W21 = dt/2 * W22 @ T (4 tiles, + Ab/Bb
//   emission). All deps are intra-pair => intra-block; __syncthreads between
//   gkt calls guards LDS reuse and T store->load visibility (same CU).
// ---------------------------------------------------------------------------
__global__ __launch_bounds__(256) void pair64(const float* __restrict__ A,
    float* __restrict__ W, float* __restrict__ T, float* __restrict__ Ab,
    float* __restrict__ Bbc, float* __restrict__ V, const float* __restrict__ Bv)
{
    __shared__ float smem[4608];
    const int o = blockIdx.x * 128;
#pragma unroll
    for (int t = 0; t < 4; ++t) {            // phase 1: T tiles
        int it = t >> 1, jt = t & 1;
        gkt(smem, A + (size_t)(o + 64) * NDIM + o, NDIM,
            W + (size_t)o * NDIM + o, NDIM,
            T + (size_t)(o + 64) * NDIM + o, NDIM,
            it * 32, jt * 32, 64, 1.f);
        __syncthreads();
    }
#pragma unroll
    for (int t = 0; t < 4; ++t) {            // phase 2: W21 tiles + Ab/Bb
        int it = t >> 1, jt = t & 1;
        gkt(smem, W + (size_t)(o + 64) * NDIM + (o + 64), NDIM,
            T + (size_t)(o + 64) * NDIM + o, NDIM,
            W + (size_t)(o + 64) * NDIM + o, NDIM,
            it * 32, jt * 32, 64, DT2F, Ab, Bbc, V, Bv, o + 64, o);
        __syncthreads();
    }
}

// ---------------------------------------------------------------------------
// pair combines for s=128,256. W11 lower-tri => clip K start on pairA2;
// W22 lower-tri => clip K end on pairB2. pairB2 emits Ab/Bb.
// ---------------------------------------------------------------------------
__global__ __launch_bounds__(256) void pairA2(const float* __restrict__ A,
    const float* __restrict__ W, float* __restrict__ T, int s)
{
    __shared__ float smem[4608];
    int ntx = s >> 5;
    int tile = blockIdx.x;
    int it = tile / ntx, jt = tile - it * ntx;
    int o = blockIdx.y * 2 * s;
    int col0 = jt * 32, k0 = col0 & ~63;       // B=W11 col j needs k>=j
    gkt(smem, A + (size_t)(o + s) * NDIM + o + k0, NDIM,
        W + (size_t)(o + k0) * NDIM + o, NDIM,
        T + (size_t)(o + s) * NDIM + o, NDIM,
        it * 32, col0, s - k0, 1.f);
}

__global__ __launch_bounds__(256) void pairB2(float* __restrict__ W,
    const float* __restrict__ T, int s, float* __restrict__ Ab,
    float* __restrict__ Bbc, float* __restrict__ V, const float* __restrict__ Bv)
{
    __shared__ float smem[4608];
    int ntx = s >> 5;
    int tile = blockIdx.x;
    int it = tile / ntx, jt = tile - it * ntx;
    int o = blockIdx.y * 2 * s;
    int ke = (it * 32 + 95) & ~63; if (ke > s) ke = s;  // A=W22 row r: k<=r
    gkt(smem, W + (size_t)(o + s) * NDIM + (o + s), NDIM,
        T + (size_t)(o + s) * NDIM + o, NDIM,
        W + (size_t)(o + s) * NDIM + o, NDIM,
        it * 32, jt * 32, ke, DT2F, Ab, Bbc, V, Bv, o + s, o);
}

// ---------------------------------------------------------------------------
// round_kernel: one doubling round, exact-size 1-D grid (R4-verified).
//  t<136          : z2  gnew = g@g, lower tiles, K clipped to band.
//  tailmode 0     : t-136 < nz -> z0 (V doubling); else z1 (Crows doubling).
//  tailmode 1 (r10): crow1024 (2) | kv (256) | build_u (2048).
//  tailmode 2 (r11/r12): scan round (2048 tasks), G = Gscan, offset o.
// ---------------------------------------------------------------------------
__global__ __launch_bounds__(256) void round_kernel(
    const float* __restrict__ g, float* __restrict__ gnew,
    float* __restrict__ V, float* __restrict__ Crows,
    int m, int lognx, int nz, int tailmode,
    const float* __restrict__ Gscan, const float* __restrict__ Ab,
    const float* __restrict__ x, const float* __restrict__ hs,
    const float* __restrict__ Bbc, float* __restrict__ kv,
    float* __restrict__ U, const float* __restrict__ Zin,
    float* __restrict__ Zout, float* __restrict__ Hmat,
    float* __restrict__ hfin, int o)
{
    __shared__ float smem[4608];
    const int t = blockIdx.x;
    const int tid = threadIdx.x;
    const int wv = tid >> 6, lane = tid & 63;

    if (t < 136) {                                   // z2 lower tile
        int it, jt;
        tri_decode(t, it, jt);
        int k0 = (jt * 32) & ~63;
        int ke = (it * 32 + 95) & ~63; if (ke > NDIM) ke = NDIM;
        gkt(smem, g + k0, NDIM, g + (size_t)k0 * NDIM, NDIM,
            gnew, NDIM, it * 32, jt * 32, ke - k0, 1.f);
        return;
    }
    int u = t - 136;
    if (tailmode == 0) {
        int nmx = (m >= 32) ? (m >> 5) : 1;
        if (u < nz) {                                // z0: V doubling
            int it = u >> lognx, jt = u & (nmx - 1);
            int ke = (it * 32 + 95) & ~63; if (ke > NDIM) ke = NDIM;
            gkt(smem, g, NDIM, V, TCH, V + m, TCH, it * 32, jt * 32, ke, 1.f);
        } else {                                     // z1: Crows doubling
            u -= nz;
            int it = u >> 4, jt = u & 15;
            int col0 = jt * 32, k0 = col0 & ~63;
            gkt(smem, Crows + k0, NDIM, g + (size_t)k0 * NDIM, NDIM,
                Crows + (size_t)m * NDIM, NDIM, it * 32, col0, NDIM - k0, 1.f);
        }
    } else if (tailmode == 1) {
        if (u < 2) {                                 // crow1024 = Crows[1023]@Ab
            float* cs = smem;
            for (int k = tid; k < NDIM; k += 256)
                cs[k] = Crows[(size_t)1023 * NDIM + k];
            __syncthreads();
            int j = u * 256 + tid;
            int k0 = j & ~63;                        // Ab col j: k>=j (band)
            float acc = 0.f;
            for (int k = k0; k < NDIM; k += 4) {
                acc += cs[k]     * Ab[(size_t)k * NDIM + j]
                     + cs[k + 1] * Ab[(size_t)(k + 1) * NDIM + j]
                     + cs[k + 2] * Ab[(size_t)(k + 2) * NDIM + j]
                     + cs[k + 3] * Ab[(size_t)(k + 3) * NDIM + j];
            }
            Crows[(size_t)1024 * NDIM + j] = acc;
        } else if (u < 258) {                        // kv[j] = Crows[j].Bb
            int j = (u - 2) * 4 + wv;
            const float* cr = Crows + (size_t)j * NDIM;
            float dot = 0.f;
#pragma unroll
            for (int rr = 0; rr < 2; ++rr) {
                int oo = rr * 256 + lane * 4;
                float4 c4 = *(const float4*)(cr + oo);
                float4 b4 = *(const float4*)(Bbc + oo);
                dot += c4.x * b4.x + c4.y * b4.y + c4.z * b4.z + c4.w * b4.w;
            }
#pragma unroll
            for (int off = 32; off; off >>= 1) dot += __shfl_xor(dot, off, 64);
            if (lane == 0) kv[j] = dot;
        } else {                                     // build_u
            int wid = (u - 258) * 4 + wv;
            int p = wid & (PCH - 1), i = wid >> 4;
            const float* vr = V + (size_t)i * TCH;
            const float* xc = x + p * TCH;
            float s = 0.f;
#pragma unroll
            for (int rr = 0; rr < 16; ++rr) {
                int t2 = (rr << 6) + lane;
                s += vr[TCH - 1 - t2] * xc[t2];
            }
            if (p == 0) {                            // + GA@h0, GA lower-tri
                const float* gr = Gscan + (size_t)i * NDIM;
                int rmax = i >> 6;
                for (int rr = 0; rr <= rmax; ++rr) {
                    int k = (rr << 6) + lane;
                    if (k <= i) s += gr[k] * hs[k];
                }
            }
#pragma unroll
            for (int off = 32; off; off >>= 1) s += __shfl_xor(s, off, 64);
            if (lane == 0) U[(size_t)p * NDIM + i] = s;
        }
    } else {                                         // merged scan round
        scan_task(u, Gscan, Zin, Zout, hs, Hmat, hfin, o, 0);
    }
}

// ---------------------------------------------------------------------------
// scan_round: standalone Kogge-Stone round (offsets 4 and 8).
// ---------------------------------------------------------------------------
__global__ __launch_bounds__(256) void scan_round(const float* __restrict__ G,
    const float* __restrict__ Zold, float* __restrict__ Znew,
    const float* __restrict__ hs, float* __restrict__ Hmat,
    float* __restrict__ hfin, int o, int last)
{
    scan_task(blockIdx.x, G, Zold, Znew, hs, Hmat, hfin, o, last);
}

// ---------------------------------------------------------------------------
// emit: y[p*T+s] = Crows[s+1].Hmat[p] + sum_{t<=s} kv[s-t]*x[p*T+t].
// ---------------------------------------------------------------------------
__global__ __launch_bounds__(256) void emit(const float* __restrict__ Crows,
    const float* __restrict__ Hmat, const float* __restrict__ kv,
    const float* __restrict__ x, float* __restrict__ out)
{
    int wid = blockIdx.x * 4 + (threadIdx.x >> 6);   // 0..16383
    int lane = threadIdx.x & 63;
    int p = wid & (PCH - 1), s = wid >> 4;
    const float* cr = Crows + (size_t)(s + 1) * NDIM;
    const float* hp = Hmat + (size_t)p * NDIM;
    float dot = 0.f;
#pragma unroll
    for (int r = 0; r < 2; ++r) {
        int o = r * 256 + lane * 4;
        float4 c = *(const float4*)(cr + o);
        float4 h = *(const float4*)(hp + o);
        dot += c.x * h.x + c.y * h.y + c.z * h.z + c.w * h.w;
    }
    const float* xc = x + p * TCH;
    int rmax = s >> 6;
    for (int r = 0; r <= rmax; ++r) {
        int t = (r << 6) + lane;
        if (t <= s) dot += kv[s - t] * xc[t];
    }
#pragma unroll
    for (int off = 32; off; off >>= 1) dot += __shfl_xor(dot, off, 64);
    if (lane == 0) out[p * TCH + s] = dot;
}

// ---------------------------------------------------------------------------
extern "C" void kernel_launch(void* const* d_in, const int* in_sizes, int n_in,
                              void* d_out, int out_size, void* d_ws, size_t ws_size,
                              hipStream_t stream)
{
    (void)in_sizes; (void)n_in; (void)out_size; (void)ws_size;
    const float* x  = (const float*)d_in[0];
    const float* hs = (const float*)d_in[1];
    const float* A  = (const float*)d_in[2];
    const float* Bv = (const float*)d_in[3];
    const float* C  = (const float*)d_in[4];
    float* out = (float*)d_out;                 // [y (16384) | h_final (512)]

    float* ws     = (float*)d_ws;
    float* Ab     = ws;
    float* P0     = Ab + MM;
    float* P1     = P0 + MM;
    float* GA     = P1 + MM;                    // Ab^1024
    float* GB     = GA + MM;                    // Ab^2048
    float* GC     = GB + MM;                    // Ab^4096
    float* GD     = GC + MM;                    // Ab^8192
    float* V      = GD + MM;                    // 512 x 1024
    float* Crows  = V + NDIM * TCH;             // 1025 x 512 (row 1024 below)
    float* CrowsW = Crows + TCH * NDIM;         // W alias + crow1024 row
    float* kv     = CrowsW + TCH * NDIM;        // 1024
    float* Bbc    = kv + TCH;                   // 512
    float* U      = Bbc + NDIM;                 // 16 x 512
    float* Z0     = U + PCH * NDIM;             // 16 x 512
    float* Z1     = Z0 + PCH * NDIM;            // 16 x 512
    float* Hmat   = Z1 + PCH * NDIM;            // 16 x 512

    float* W = CrowsW;  // W dead after the pair levels; row 0 = crow1024 later.
    float* T = P0;      // pair temp (strictly-lower 64-blocks only); round 0
                        // rewrites all lower tiles; diag-uppers from zero_diag.

    // ---- init: diag inverses (W + Ab diag + Bb diag part), power-buffer
    //      diag-upper zeroing, Crows[0] = C ----
    zero_diag<<<57, 256, 0, stream>>>(A, W, P0, Ab, Bbc, V, Crows, Bv, C);

    // ---- blocked inversion; W21 writers emit Ab = 2W and Bb partials ----
    pair64<<<4, 256, 0, stream>>>(A, W, T, Ab, Bbc, V, Bv);
    for (int s = 128; s <= 256; s <<= 1) {
        int np = NDIM / (2 * s);
        int tiles = (s >> 5) * (s >> 5);
        dim3 grid(tiles, np);
        pairA2<<<grid, 256, 0, stream>>>(A, W, T, s);
        pairB2<<<grid, 256, 0, stream>>>(W, T, s, Ab, Bbc, V, Bv);
    }

    // ---- 13 doubling rounds (chain-depth minimum); rounds 10-12 carry the
    //      per-chunk tail work (cb) and the first two scan rounds ----
    const float* g = Ab;
    float* gouts[13] = {P0, P1, P0, P1, P0, P1, P0, P1, P0, GA, GB, GC, GD};
    int m = 1;
    for (int r = 0; r < 13; ++r) {
        int nmx = (m >= 32) ? (m >> 5) : 1;
        int lognx = (r >= 5) ? (r - 5) : 0;
        int nz = (m < TCH) ? 16 * nmx : 0;
        int tailmode = 0, ntail = 0, oo = 0;
        const float* Gs = GA; const float* Zi = U; float* Zo = Z0;
        if (r == 10)      { tailmode = 1; ntail = 2306; }
        else if (r == 11) { tailmode = 2; ntail = 2048; oo = 1; }
        else if (r == 12) { tailmode = 2; ntail = 2048; oo = 2; Gs = GB;
                            Zi = Z0; Zo = Z1; }
        round_kernel<<<136 + 2 * nz + ntail, 256, 0, stream>>>(
            g, gouts[r], V, Crows, m, lognx, nz, tailmode, Gs, Ab,
            x, hs, Bbc, kv, U, Zi, Zo, Hmat, out + LSEQ, oo);
        g = gouts[r];
        m <<= 1;
    }

    // ---- remaining Kogge-Stone rounds: offsets 4, 8 ----
    scan_round<<<2048, 256, 0, stream>>>(GC, Z1, Z0, hs, Hmat, out + LSEQ, 4, 0);
    scan_round<<<2048, 256, 0, stream>>>(GD, Z0, Z1, hs, Hmat, out + LSEQ, 8, 1);

    // ---- fused epilogue ----
    emit<<<4096, 256, 0, stream>>>(Crows, Hmat, kv, x, out);
}

// Round 11
// 265.398 us; speedup vs baseline: 1.6733x; 1.6733x over previous
//
#include <hip/hip_runtime.h>

// N=512 state dim, L=16384 steps, chunk T=1024, P=16 chunks.
#define NDIM 512
#define LSEQ 16384
#define TCH  1024
#define PCH  16
#define MM   (NDIM * NDIM)

#define DTF  (1.0f/16384.0f)
#define DT2F (0.5f/16384.0f)

// ---------------------------------------------------------------------------
// gkt: 32x32-output GEMM task, 4-wave K-split with private LDS staging and
// cross-wave LDS reduce. K must be a multiple of 64. (R4-verified core: 1-deep
// register prefetch, no per-step barriers; only barrier is pre-reduce.)
// Optional epilogue (gr0>=0, used by W21 writers): also emit Ab = 2*val
// (strictly-lower blocks, no -I) and atomicAdd the Bb row-partial
// dt*val.Bv into Bbc and V[:,0]. gr0/gc0 = global coords of D's origin.
// NOTE when one block runs several gkt calls back-to-back the CALLER must
// __syncthreads() between calls (LDS reuse + D->B visibility).
// ---------------------------------------------------------------------------
__device__ __forceinline__ void gkt(float* smem,
    const float* A, int lda, const float* B, int ldb,
    float* D, int ldd, int row0, int col0, int K, float alpha,
    float* Abe = nullptr, float* Bbce = nullptr, float* Ve = nullptr,
    const float* Bve = nullptr, int gr0 = -1, int gc0 = 0)
{
    const int tid  = threadIdx.x;
    const int w    = tid >> 6;
    const int lane = tid & 63;
    const int ty = lane >> 3, tx = lane & 7;          // 8x8 lane grid, 4x4 micro

    float* As = smem + w * 1152;          // As[k][r] = As[k*36 + r]
    float* Bs = As + 576;                 // Bs[k][c] = Bs[k*36 + c]

    const int Kc    = K >> 2;             // per-wave K chunk (mult of 16)
    const int steps = Kc >> 4;
    const int kbase = w * Kc;

    const int ar  = lane >> 2, acg = (lane & 3) * 4;  // A-stage lane map
    const int bkr = lane >> 3, bcg = (lane & 7) * 4;  // B-stage lane map
    const float* Ap0 = A + (size_t)(row0 + ar) * lda + kbase + acg;
    const float* Ap1 = Ap0 + (size_t)16 * lda;
    const float* Bp0 = B + (size_t)(kbase + bkr) * ldb + col0 + bcg;
    const float* Bp1 = Bp0 + (size_t)8 * ldb;

    float4 av0 = *(const float4*)Ap0;
    float4 av1 = *(const float4*)Ap1;
    float4 bv0 = *(const float4*)Bp0;
    float4 bv1 = *(const float4*)Bp1;

    float acc[4][4] = {};

    for (int s = 0; s < steps; ++s) {
        As[(acg + 0) * 36 + ar] = av0.x;
        As[(acg + 1) * 36 + ar] = av0.y;
        As[(acg + 2) * 36 + ar] = av0.z;
        As[(acg + 3) * 36 + ar] = av0.w;
        As[(acg + 0) * 36 + ar + 16] = av1.x;
        As[(acg + 1) * 36 + ar + 16] = av1.y;
        As[(acg + 2) * 36 + ar + 16] = av1.z;
        As[(acg + 3) * 36 + ar + 16] = av1.w;
        *(float4*)(Bs + bkr * 36 + bcg)       = bv0;
        *(float4*)(Bs + (bkr + 8) * 36 + bcg) = bv1;

        if (s + 1 < steps) {
            int ko = (s + 1) * 16;
            av0 = *(const float4*)(Ap0 + ko);
            av1 = *(const float4*)(Ap1 + ko);
            bv0 = *(const float4*)(Bp0 + (size_t)ko * ldb);
            bv1 = *(const float4*)(Bp1 + (size_t)ko * ldb);
        }

#pragma unroll
        for (int kk = 0; kk < 16; ++kk) {
            float4 a = *(const float4*)(As + kk * 36 + 4 * ty);
            float4 b = *(const float4*)(Bs + kk * 36 + 4 * tx);
            acc[0][0] += a.x * b.x; acc[0][1] += a.x * b.y; acc[0][2] += a.x * b.z; acc[0][3] += a.x * b.w;
            acc[1][0] += a.y * b.x; acc[1][1] += a.y * b.y; acc[1][2] += a.y * b.z; acc[1][3] += a.y * b.w;
            acc[2][0] += a.z * b.x; acc[2][1] += a.z * b.y; acc[2][2] += a.z * b.z; acc[2][3] += a.z * b.w;
            acc[3][0] += a.w * b.x; acc[3][1] += a.w * b.y; acc[3][2] += a.w * b.z; acc[3][3] += a.w * b.w;
        }
    }

    float* red = smem + w * 1152;
#pragma unroll
    for (int i = 0; i < 4; ++i)
        *(float4*)(red + (4 * ty + i) * 32 + 4 * tx) =
            make_float4(acc[i][0], acc[i][1], acc[i][2], acc[i][3]);
    __syncthreads();

    float4 s0 = *(const float4*)(smem + 0 * 1152 + tid * 4);
    float4 s1 = *(const float4*)(smem + 1 * 1152 + tid * 4);
    float4 s2 = *(const float4*)(smem + 2 * 1152 + tid * 4);
    float4 s3 = *(const float4*)(smem + 3 * 1152 + tid * 4);
    float4 r4 = make_float4(alpha * (s0.x + s1.x + s2.x + s3.x),
                            alpha * (s0.y + s1.y + s2.y + s3.y),
                            alpha * (s0.z + s1.z + s2.z + s3.z),
                            alpha * (s0.w + s1.w + s2.w + s3.w));
    int r = tid >> 3, c = (tid & 7) * 4;
    // scalar stores: D base may be only 4B-aligned (V+m slab writes, m=1,2)
    float* dp = D + (size_t)(row0 + r) * ldd + col0 + c;
    dp[0] = r4.x; dp[1] = r4.y; dp[2] = r4.z; dp[3] = r4.w;

    if (gr0 >= 0) {   // W21 writer: emit Ab = 2*W21 and Bb row-partials
        int grow = gr0 + row0 + r, gcol = gc0 + col0 + c;
        *(float4*)(Abe + (size_t)grow * NDIM + gcol) =
            make_float4(2.f * r4.x, 2.f * r4.y, 2.f * r4.z, 2.f * r4.w);
        float pv = r4.x * Bve[gcol]     + r4.y * Bve[gcol + 1]
                 + r4.z * Bve[gcol + 2] + r4.w * Bve[gcol + 3];
        pv += __shfl_xor(pv, 1, 64);     // reduce across the 8 col-threads
        pv += __shfl_xor(pv, 2, 64);     // of this row (lane-aligned group)
        pv += __shfl_xor(pv, 4, 64);
        if ((tid & 7) == 0) {
            float bb = DTF * pv;
            atomicAdd(&Bbce[grow], bb);
            atomicAdd(&Ve[(size_t)grow * TCH], bb);
        }
    }
}

// triangular tile decode: t -> (it, jt) with jt <= it
__device__ __forceinline__ void tri_decode(int t, int& it, int& jt)
{
    it = (int)((sqrtf(8.f * (float)t + 1.f) - 1.f) * 0.5f);
    while ((it + 1) * (it + 2) / 2 <= t) ++it;
    while (it * (it + 1) / 2 > t) --it;
    jt = t - it * (it + 1) / 2;
}

// ---------------------------------------------------------------------------
// scan_task: one Kogge-Stone task (4 waves = 4 (p,i) pairs), G lower-tri.
// ---------------------------------------------------------------------------
__device__ __forceinline__ void scan_task(int task, const float* G,
    const float* Zold, float* Znew, const float* hs, float* Hmat,
    float* hfin, int o, int last)
{
    int wid = task * 4 + (threadIdx.x >> 6);
    int lane = threadIdx.x & 63;
    int p = wid & (PCH - 1), i = wid >> 4;
    float dot = 0.f;
    if (p >= o) {
        const float* gr = G + (size_t)i * NDIM;
        const float* zc = Zold + (size_t)(p - o) * NDIM;
        int rmax = i >> 6;
        for (int r = 0; r <= rmax; ++r) {
            int k = (r << 6) + lane;
            if (k <= i) dot += gr[k] * zc[k];
        }
#pragma unroll
        for (int off = 32; off; off >>= 1) dot += __shfl_xor(dot, off, 64);
    }
    if (lane == 0) {
        float z = Zold[(size_t)p * NDIM + i] + dot;
        Znew[(size_t)p * NDIM + i] = z;
        if (last) {
            if (p < PCH - 1) Hmat[(size_t)(p + 1) * NDIM + i] = z;
            else hfin[i] = z;
            if (p == 0) Hmat[i] = hs[i];
        }
    }
}

// ---------------------------------------------------------------------------
// zero_diag: fused one-time init — spill-free (R9) + separate re-stage
// buffer sh2 (R11 defensive tweak: no aliasing/ordering argument needed).
//  t<8  : invert diagonal 64x64 block t of (I - dt/2*A) into W. Solve phase
//         (wave 0, xcol[64] in regs) writes X into sh2 (not sh). After a
//         uniform barrier, all 256 threads emit the Ab diag block (2X - I,
//         exact-zero uppers) and the Bb diag partials FROM sh2.
//  8<=t<56: zero strictly-upper part of diagonal 64-block d of power buffer q
//         (P0..GD) — the only upper entries the 64-aligned K-clips ever read.
//  t==56: Crows[0] = C.
// ---------------------------------------------------------------------------
__global__ __launch_bounds__(256) void zero_diag(const float* __restrict__ A,
    float* __restrict__ W, float* __restrict__ P0, float* __restrict__ Ab,
    float* __restrict__ Bbc, float* __restrict__ V, float* __restrict__ Crows,
    const float* __restrict__ Bv, const float* __restrict__ C)
{
    __shared__ float sh[64][65];
    __shared__ float sh2[64][65];
    const int t = blockIdx.x, tid = threadIdx.x;
    if (t < 8) {
        const int base = t * 64;
        for (int idx = tid; idx < 4096; idx += 256) {
            int r = idx >> 6, c = idx & 63;
            sh[r][c] = ((r == c) ? 1.f : 0.f)
                     - DT2F * A[(size_t)(base + r) * NDIM + base + c];
        }
        __syncthreads();
        if (tid < 64) {
            const int lane = tid;
            float xcol[64];
#pragma unroll
            for (int i = 0; i < 64; ++i) {
                float dot = 0.f;
#pragma unroll
                for (int k = 0; k < i; ++k) dot += sh[i][k] * xcol[k];
                xcol[i] = (((lane == i) ? 1.f : 0.f) - dot) / sh[i][i];
            }
#pragma unroll
            for (int k = 0; k < 64; ++k) {
                W[(size_t)(base + k) * NDIM + base + lane] = xcol[k];
                sh2[k][lane] = xcol[k];          // separate buffer: no alias
            }
        }
        __syncthreads();
        // emission from sh2 by all 256 threads (trivial register pressure)
        for (int idx = tid; idx < 4096; idx += 256) {
            int r = idx >> 6, c = idx & 63;
            Ab[(size_t)(base + r) * NDIM + base + c] =
                2.f * sh2[r][c] - ((r == c) ? 1.f : 0.f);
        }
        {   // Bb diag partial: row k handled by 4 threads (tid = 4k+q)
            int k = tid >> 2, q = tid & 3;
            const float* xr = &sh2[k][0];
            float pv = 0.f;
#pragma unroll
            for (int c = 0; c < 16; ++c)
                pv += xr[q * 16 + c] * Bv[base + q * 16 + c];
            pv += __shfl_xor(pv, 1, 64);     // 4-lane group reduce (aligned)
            pv += __shfl_xor(pv, 2, 64);
            if (q == 0) {
                float bb = DTF * pv;
                Bbc[base + k] = bb;                  // plain store (base part)
                V[(size_t)(base + k) * TCH] = bb;
            }
        }
    } else if (t < 56) {
        const int q = (t - 8) >> 3, d = (t - 8) & 7;
        float* buf = P0 + (size_t)q * MM;
        for (int idx = tid; idx < 4096; idx += 256) {
            int r = idx >> 6, c = idx & 63;
            if (c > r) buf[(size_t)(d * 64 + r) * NDIM + d * 64 + c] = 0.f;
        }
    } else {
        Crows[tid]       = C[tid];
        Crows[tid + 256] = C[tid + 256];
    }
}

// ---------------------------------------------------------------------------
// pair64: merged s=64 pair level — one block per pair, both phases.
//   T = A21 @ W11 (4 tiles), then W21 = dt/2 * W22 @ T (4 tiles, + Ab/Bb
//   emission). All deps are intra-pair => intra-block; __syncthreads between
//   gkt calls guards LDS reuse and T store->load visibility (same CU).
// ---------------------------------------------------------------------------
__global__ __launch_bounds__(256) void pair64(const float* __restrict__ A,
    float* __restrict__ W, float* __restrict__ T, float* __restrict__ Ab,
    float* __restrict__ Bbc, float* __restrict__ V, const float* __restrict__ Bv)
{
    __shared__ float smem[4608];
    const int o = blockIdx.x * 128;
#pragma unroll
    for (int t = 0; t < 4; ++t) {            // phase 1: T tiles
        int it = t >> 1, jt = t & 1;
        gkt(smem, A + (size_t)(o + 64) * NDIM + o, NDIM,
            W + (size_t)o * NDIM + o, NDIM,
            T + (size_t)(o + 64) * NDIM + o, NDIM,
            it * 32, jt * 32, 64, 1.f);
        __syncthreads();
    }
#pragma unroll
    for (int t = 0; t < 4; ++t) {            // phase 2: W21 tiles + Ab/Bb
        int it = t >> 1, jt = t & 1;
        gkt(smem, W + (size_t)(o + 64) * NDIM + (o + 64), NDIM,
            T + (size_t)(o + 64) * NDIM + o, NDIM,
            W + (size_t)(o + 64) * NDIM + o, NDIM,
            it * 32, jt * 32, 64, DT2F, Ab, Bbc, V, Bv, o + 64, o);
        __syncthreads();
    }
}

// ---------------------------------------------------------------------------
// pair combines for s=128,256. W11 lower-tri => clip K start on pairA2;
// W22 lower-tri => clip K end on pairB2. pairB2 emits Ab/Bb.
// ---------------------------------------------------------------------------
__global__ __launch_bounds__(256) void pairA2(const float* __restrict__ A,
    const float* __restrict__ W, float* __restrict__ T, int s)
{
    __shared__ float smem[4608];
    int ntx = s >> 5;
    int tile = blockIdx.x;
    int it = tile / ntx, jt = tile - it * ntx;
    int o = blockIdx.y * 2 * s;
    int col0 = jt * 32, k0 = col0 & ~63;       // B=W11 col j needs k>=j
    gkt(smem, A + (size_t)(o + s) * NDIM + o + k0, NDIM,
        W + (size_t)(o + k0) * NDIM + o, NDIM,
        T + (size_t)(o + s) * NDIM + o, NDIM,
        it * 32, col0, s - k0, 1.f);
}

__global__ __launch_bounds__(256) void pairB2(float* __restrict__ W,
    const float* __restrict__ T, int s, float* __restrict__ Ab,
    float* __restrict__ Bbc, float* __restrict__ V, const float* __restrict__ Bv)
{
    __shared__ float smem[4608];
    int ntx = s >> 5;
    int tile = blockIdx.x;
    int it = tile / ntx, jt = tile - it * ntx;
    int o = blockIdx.y * 2 * s;
    int ke = (it * 32 + 95) & ~63; if (ke > s) ke = s;  // A=W22 row r: k<=r
    gkt(smem, W + (size_t)(o + s) * NDIM + (o + s), NDIM,
        T + (size_t)(o + s) * NDIM + o, NDIM,
        W + (size_t)(o + s) * NDIM + o, NDIM,
        it * 32, jt * 32, ke, DT2F, Ab, Bbc, V, Bv, o + s, o);
}

// ---------------------------------------------------------------------------
// round_kernel: one doubling round, exact-size 1-D grid (R4-verified).
//  t<136          : z2  gnew = g@g, lower tiles, K clipped to band.
//  tailmode 0     : t-136 < nz -> z0 (V doubling); else z1 (Crows doubling).
//  tailmode 1 (r10): crow1024 (2) | kv (256) | build_u (2048).
//  tailmode 2 (r11/r12): scan round (2048 tasks), G = Gscan, offset o.
// ---------------------------------------------------------------------------
__global__ __launch_bounds__(256) void round_kernel(
    const float* __restrict__ g, float* __restrict__ gnew,
    float* __restrict__ V, float* __restrict__ Crows,
    int m, int lognx, int nz, int tailmode,
    const float* __restrict__ Gscan, const float* __restrict__ Ab,
    const float* __restrict__ x, const float* __restrict__ hs,
    const float* __restrict__ Bbc, float* __restrict__ kv,
    float* __restrict__ U, const float* __restrict__ Zin,
    float* __restrict__ Zout, float* __restrict__ Hmat,
    float* __restrict__ hfin, int o)
{
    __shared__ float smem[4608];
    const int t = blockIdx.x;
    const int tid = threadIdx.x;
    const int wv = tid >> 6, lane = tid & 63;

    if (t < 136) {                                   // z2 lower tile
        int it, jt;
        tri_decode(t, it, jt);
        int k0 = (jt * 32) & ~63;
        int ke = (it * 32 + 95) & ~63; if (ke > NDIM) ke = NDIM;
        gkt(smem, g + k0, NDIM, g + (size_t)k0 * NDIM, NDIM,
            gnew, NDIM, it * 32, jt * 32, ke - k0, 1.f);
        return;
    }
    int u = t - 136;
    if (tailmode == 0) {
        int nmx = (m >= 32) ? (m >> 5) : 1;
        if (u < nz) {                                // z0: V doubling
            int it = u >> lognx, jt = u & (nmx - 1);
            int ke = (it * 32 + 95) & ~63; if (ke > NDIM) ke = NDIM;
            gkt(smem, g, NDIM, V, TCH, V + m, TCH, it * 32, jt * 32, ke, 1.f);
        } else {                                     // z1: Crows doubling
            u -= nz;
            int it = u >> 4, jt = u & 15;
            int col0 = jt * 32, k0 = col0 & ~63;
            gkt(smem, Crows + k0, NDIM, g + (size_t)k0 * NDIM, NDIM,
                Crows + (size_t)m * NDIM, NDIM, it * 32, col0, NDIM - k0, 1.f);
        }
    } else if (tailmode == 1) {
        if (u < 2) {                                 // crow1024 = Crows[1023]@Ab
            float* cs = smem;
            for (int k = tid; k < NDIM; k += 256)
                cs[k] = Crows[(size_t)1023 * NDIM + k];
            __syncthreads();
            int j = u * 256 + tid;
            int k0 = j & ~63;                        // Ab col j: k>=j (band)
            float acc = 0.f;
            for (int k = k0; k < NDIM; k += 4) {
                acc += cs[k]     * Ab[(size_t)k * NDIM + j]
                     + cs[k + 1] * Ab[(size_t)(k + 1) * NDIM + j]
                     + cs[k + 2] * Ab[(size_t)(k + 2) * NDIM + j]
                     + cs[k + 3] * Ab[(size_t)(k + 3) * NDIM + j];
            }
            Crows[(size_t)1024 * NDIM + j] = acc;
        } else if (u < 258) {                        // kv[j] = Crows[j].Bb
            int j = (u - 2) * 4 + wv;
            const float* cr = Crows + (size_t)j * NDIM;
            float dot = 0.f;
#pragma unroll
            for (int rr = 0; rr < 2; ++rr) {
                int oo = rr * 256 + lane * 4;
                float4 c4 = *(const float4*)(cr + oo);
                float4 b4 = *(const float4*)(Bbc + oo);
                dot += c4.x * b4.x + c4.y * b4.y + c4.z * b4.z + c4.w * b4.w;
            }
#pragma unroll
            for (int off = 32; off; off >>= 1) dot += __shfl_xor(dot, off, 64);
            if (lane == 0) kv[j] = dot;
        } else {                                     // build_u
            int wid = (u - 258) * 4 + wv;
            int p = wid & (PCH - 1), i = wid >> 4;
            const float* vr = V + (size_t)i * TCH;
            const float* xc = x + p * TCH;
            float s = 0.f;
#pragma unroll
            for (int rr = 0; rr < 16; ++rr) {
                int t2 = (rr << 6) + lane;
                s += vr[TCH - 1 - t2] * xc[t2];
            }
            if (p == 0) {                            // + GA@h0, GA lower-tri
                const float* gr = Gscan + (size_t)i * NDIM;
                int rmax = i >> 6;
                for (int rr = 0; rr <= rmax; ++rr) {
                    int k = (rr << 6) + lane;
                    if (k <= i) s += gr[k] * hs[k];
                }
            }
#pragma unroll
            for (int off = 32; off; off >>= 1) s += __shfl_xor(s, off, 64);
            if (lane == 0) U[(size_t)p * NDIM + i] = s;
        }
    } else {                                         // merged scan round
        scan_task(u, Gscan, Zin, Zout, hs, Hmat, hfin, o, 0);
    }
}

// ---------------------------------------------------------------------------
// scan_round: standalone Kogge-Stone round (offsets 4 and 8).
// ---------------------------------------------------------------------------
__global__ __launch_bounds__(256) void scan_round(const float* __restrict__ G,
    const float* __restrict__ Zold, float* __restrict__ Znew,
    const float* __restrict__ hs, float* __restrict__ Hmat,
    float* __restrict__ hfin, int o, int last)
{
    scan_task(blockIdx.x, G, Zold, Znew, hs, Hmat, hfin, o, last);
}

// ---------------------------------------------------------------------------
// emit: y[p*T+s] = Crows[s+1].Hmat[p] + sum_{t<=s} kv[s-t]*x[p*T+t].
// ---------------------------------------------------------------------------
__global__ __launch_bounds__(256) void emit(const float* __restrict__ Crows,
    const float* __restrict__ Hmat, const float* __restrict__ kv,
    const float* __restrict__ x, float* __restrict__ out)
{
    int wid = blockIdx.x * 4 + (threadIdx.x >> 6);   // 0..16383
    int lane = threadIdx.x & 63;
    int p = wid & (PCH - 1), s = wid >> 4;
    const float* cr = Crows + (size_t)(s + 1) * NDIM;
    const float* hp = Hmat + (size_t)p * NDIM;
    float dot = 0.f;
#pragma unroll
    for (int r = 0; r < 2; ++r) {
        int o = r * 256 + lane * 4;
        float4 c = *(const float4*)(cr + o);
        float4 h = *(const float4*)(hp + o);
        dot += c.x * h.x + c.y * h.y + c.z * h.z + c.w * h.w;
    }
    const float* xc = x + p * TCH;
    int rmax = s >> 6;
    for (int r = 0; r <= rmax; ++r) {
        int t = (r << 6) + lane;
        if (t <= s) dot += kv[s - t] * xc[t];
    }
#pragma unroll
    for (int off = 32; off; off >>= 1) dot += __shfl_xor(dot, off, 64);
    if (lane == 0) out[p * TCH + s] = dot;
}

// ---------------------------------------------------------------------------
extern "C" void kernel_launch(void* const* d_in, const int* in_sizes, int n_in,
                              void* d_out, int out_size, void* d_ws, size_t ws_size,
                              hipStream_t stream)
{
    (void)in_sizes; (void)n_in; (void)out_size; (void)ws_size;
    const float* x  = (const float*)d_in[0];
    const float* hs = (const float*)d_in[1];
    const float* A  = (const float*)d_in[2];
    const float* Bv = (const float*)d_in[3];
    const float* C  = (const float*)d_in[4];
    float* out = (float*)d_out;                 // [y (16384) | h_final (512)]

    float* ws     = (float*)d_ws;
    float* Ab     = ws;
    float* P0     = Ab + MM;
    float* P1     = P0 + MM;
    float* GA     = P1 + MM;                    // Ab^1024
    float* GB     = GA + MM;                    // Ab^2048
    float* GC     = GB + MM;                    // Ab^4096
    float* GD     = GC + MM;                    // Ab^8192
    float* V      = GD + MM;                    // 512 x 1024
    float* Crows  = V + NDIM * TCH;             // 1025 x 512 (row 1024 below)
    float* CrowsW = Crows + TCH * NDIM;         // W alias + crow1024 row
    float* kv     = CrowsW + TCH * NDIM;        // 1024
    float* Bbc    = kv + TCH;                   // 512
    float* U      = Bbc + NDIM;                 // 16 x 512
    float* Z0     = U + PCH * NDIM;             // 16 x 512
    float* Z1     = Z0 + PCH * NDIM;            // 16 x 512
    float* Hmat   = Z1 + PCH * NDIM;            // 16 x 512

    float* W = CrowsW;  // W dead after the pair levels; row 0 = crow1024 later.
    float* T = P0;      // pair temp (strictly-lower 64-blocks only); round 0
                        // rewrites all lower tiles; diag-uppers from zero_diag.

    // ---- init: diag inverses (W + Ab diag + Bb diag part), power-buffer
    //      diag-upper zeroing, Crows[0] = C ----
    zero_diag<<<57, 256, 0, stream>>>(A, W, P0, Ab, Bbc, V, Crows, Bv, C);

    // ---- blocked inversion; W21 writers emit Ab = 2W and Bb partials ----
    pair64<<<4, 256, 0, stream>>>(A, W, T, Ab, Bbc, V, Bv);
    for (int s = 128; s <= 256; s <<= 1) {
        int np = NDIM / (2 * s);
        int tiles = (s >> 5) * (s >> 5);
        dim3 grid(tiles, np);
        pairA2<<<grid, 256, 0, stream>>>(A, W, T, s);
        pairB2<<<grid, 256, 0, stream>>>(W, T, s, Ab, Bbc, V, Bv);
    }

    // ---- 13 doubling rounds (chain-depth minimum); rounds 10-12 carry the
    //      per-chunk tail work (cb) and the first two scan rounds ----
    const float* g = Ab;
    float* gouts[13] = {P0, P1, P0, P1, P0, P1, P0, P1, P0, GA, GB, GC, GD};
    int m = 1;
    for (int r = 0; r < 13; ++r) {
        int nmx = (m >= 32) ? (m >> 5) : 1;
        int lognx = (r >= 5) ? (r - 5) : 0;
        int nz = (m < TCH) ? 16 * nmx : 0;
        int tailmode = 0, ntail = 0, oo = 0;
        const float* Gs = GA; const float* Zi = U; float* Zo = Z0;
        if (r == 10)      { tailmode = 1; ntail = 2306; }
        else if (r == 11) { tailmode = 2; ntail = 2048; oo = 1; }
        else if (r == 12) { tailmode = 2; ntail = 2048; oo = 2; Gs = GB;
                            Zi = Z0; Zo = Z1; }
        round_kernel<<<136 + 2 * nz + ntail, 256, 0, stream>>>(
            g, gouts[r], V, Crows, m, lognx, nz, tailmode, Gs, Ab,
            x, hs, Bbc, kv, U, Zi, Zo, Hmat, out + LSEQ, oo);
        g = gouts[r];
        m <<= 1;
    }

    // ---- remaining Kogge-Stone rounds: offsets 4, 8 ----
    scan_round<<<2048, 256, 0, stream>>>(GC, Z1, Z0, hs, Hmat, out + LSEQ, 4, 0);
    scan_round<<<2048, 256, 0, stream>>>(GD, Z0, Z1, hs, Hmat, out + LSEQ, 8, 1);

    // ---- fused epilogue ----
    emit<<<4096, 256, 0, stream>>>(Crows, Hmat, kv, x, out);
}